// Round 7
// baseline (462.251 us; speedup 1.0000x reference)
//
#include <hip/hip_runtime.h>
#include <hip/hip_bf16.h>

typedef __bf16 bf16_t;
typedef __bf16 bf16x8 __attribute__((ext_vector_type(8)));
typedef float  f32x4  __attribute__((ext_vector_type(4)));

#define DEVFN static __device__ __forceinline__

constexpr int TOK   = 32 * 512;        // 16384 tokens
constexpr int W_OFF = TOK * 128;       // weights offset (floats) in d_out

// d_ws byte offsets
constexpr size_t WS_A_VW2 = 0;                                  // 1MB (bf16, plain rows)
constexpr size_t WS_A_WG2 = (size_t)1 << 20;                    // 1MB (bf16, plain rows)
constexpr size_t WS_BG2   = (size_t)2 << 20;                    // 16KB f32 [32][128]
constexpr size_t WS_A_FW2 = ((size_t)2 << 20) + (64u  << 10);   // 32KB (bf16, XOR-swizzled for k1 LDS)
constexpr size_t WS_A_WG1 = ((size_t)2 << 20) + (128u << 10);   // 32KB (bf16, XOR-swizzled for k1 LDS)
constexpr size_t WS_BG1   = ((size_t)2 << 20) + (192u << 10);   // 512B f32 [128]
constexpr size_t WS_A_FW1 = ((size_t)2 << 20) + (224u << 10);   // 8KB  (bf16, plain)
constexpr size_t WS_A_FSW = ((size_t)2 << 20) + (256u << 10);   // 8KB  (bf16, plain)

DEVFN float eluf(float z)  { return z > 0.0f ? z : (__expf(z) - 1.0f); }
DEVFN float sigmf(float z) { return __builtin_amdgcn_rcpf(1.0f + __expf(-z)); }
DEVFN unsigned short f2bfu(float f){ bf16_t h = (bf16_t)f; return __builtin_bit_cast(unsigned short, h); }

DEVFN uint4 pack8(f32x4 a, f32x4 b){
  uint4 r;
  r.x = (unsigned)f2bfu(a[0]) | ((unsigned)f2bfu(a[1]) << 16);
  r.y = (unsigned)f2bfu(a[2]) | ((unsigned)f2bfu(a[3]) << 16);
  r.z = (unsigned)f2bfu(b[0]) | ((unsigned)f2bfu(b[1]) << 16);
  r.w = (unsigned)f2bfu(b[2]) | ((unsigned)f2bfu(b[3]) << 16);
  return r;
}
DEVFN f32x4 mfma16(bf16x8 a, bf16x8 b, f32x4 c){
  return __builtin_amdgcn_mfma_f32_16x16x32_bf16(a, b, c, 0, 0, 0);
}
DEVFN bf16x8 asbf(uint4 u){ return __builtin_bit_cast(bf16x8, u); }

// ---------------------------------------------------------------------------
// K0 (R2-verbatim): fused gate matrices (Wg2 = vgw·vw2, Wg1 = fgw·fw2, fused
// biases), bf16 packing. VW2/WG2 slabs: PLAIN row-major [128][128] bf16.
// FW2/WG1 slabs: XOR-swizzled (k1 stages them in LDS).
// ---------------------------------------------------------------------------
__global__ void k0_prep(const float* __restrict__ fw1, const float* __restrict__ fw2,
                        const float* __restrict__ fgw, const float* __restrict__ fgb,
                        const float* __restrict__ fb2, const float* __restrict__ fsw,
                        const float* __restrict__ vw2, const float* __restrict__ vgw,
                        const float* __restrict__ vgb, const float* __restrict__ vb2,
                        unsigned char* __restrict__ ws)
{
  const int b = blockIdx.x, tid = threadIdx.x;
  if (b < 256){
    // Wg2 = vgw[v] @ vw2[v]: v = b>>3, 16 rows/block, thread: 1 row x 8 cols
    const int v  = b >> 3;
    const int k2 = (b & 7) * 16 + (tid >> 4);
    const int h0 = (tid & 15) * 8;
    const float* gw = vgw + ((size_t)v * 128 + k2) * 128;
    const float* w2 = vw2 + (size_t)v * 128 * 128;
    f32x4 a0 = {0,0,0,0}, a1 = {0,0,0,0};
    for (int k = 0; k < 128; ++k){
      float a = gw[k];
      f32x4 u = *(const f32x4*)(w2 + k*128 + h0);
      f32x4 w = *(const f32x4*)(w2 + k*128 + h0 + 4);
      #pragma unroll
      for (int e = 0; e < 4; ++e){ a0[e] = fmaf(a, u[e], a0[e]); a1[e] = fmaf(a, w[e], a1[e]); }
    }
    *(uint4*)(ws + WS_A_WG2 + (size_t)v*32768 + (size_t)k2*256 + (size_t)h0*2) = pack8(a0, a1);
    if ((b & 7) == 0 && tid < 128){
      const float* gr = vgw + ((size_t)v*128 + tid) * 128;
      const float* vb = vb2 + v*128;
      float s = vgb[v*128 + tid];
      for (int k = 0; k < 128; ++k) s = fmaf(gr[k], vb[k], s);
      ((float*)(ws + WS_BG2))[v*128 + tid] = s;
    }
  } else if (b < 288){
    // vw2 -> bf16 plain rows
    const int v = b - 256;
    const int k = tid >> 1, hh = (tid & 1) * 64;
    const float* src = vw2 + ((size_t)v*128 + k) * 128;
    #pragma unroll
    for (int i = 0; i < 8; ++i){
      int h0 = hh + i*8;
      f32x4 a = *(const f32x4*)(src + h0);
      f32x4 c = *(const f32x4*)(src + h0 + 4);
      *(uint4*)(ws + WS_A_VW2 + (size_t)v*32768 + (size_t)k*256 + (size_t)h0*2) = pack8(a, c);
    }
  } else if (b < 296){
    // Wg1 = fgw @ fw2 (+ bg1), XOR-swizzled for k1's LDS use
    const int k2 = (b - 288) * 16 + (tid >> 4);
    const int h0 = (tid & 15) * 8;
    const float* gw = fgw + (size_t)k2 * 128;
    f32x4 a0 = {0,0,0,0}, a1 = {0,0,0,0};
    for (int k = 0; k < 128; ++k){
      float a = gw[k];
      f32x4 u = *(const f32x4*)(fw2 + k*128 + h0);
      f32x4 w = *(const f32x4*)(fw2 + k*128 + h0 + 4);
      #pragma unroll
      for (int e = 0; e < 4; ++e){ a0[e] = fmaf(a, u[e], a0[e]); a1[e] = fmaf(a, w[e], a1[e]); }
    }
    unsigned blk = (unsigned)(h0 >> 3) ^ (unsigned)(k2 & 7);
    *(uint4*)(ws + WS_A_WG1 + (size_t)k2*256 + blk*16) = pack8(a0, a1);
    if (b == 288 && tid < 128){
      const float* gr = fgw + (size_t)tid * 128;
      float s = fgb[tid];
      for (int k = 0; k < 128; ++k) s = fmaf(gr[k], fb2[k], s);
      ((float*)(ws + WS_BG1))[tid] = s;
    }
  } else if (b == 296){
    // fw2 -> bf16 XOR-swizzled
    const int k = tid >> 1, hh = (tid & 1) * 64;
    const float* src = fw2 + (size_t)k * 128;
    #pragma unroll
    for (int i = 0; i < 8; ++i){
      int h0 = hh + i*8;
      f32x4 a = *(const f32x4*)(src + h0);
      f32x4 c = *(const f32x4*)(src + h0 + 4);
      unsigned blk = (unsigned)(h0 >> 3) ^ (unsigned)(k & 7);
      *(uint4*)(ws + WS_A_FW2 + (size_t)k*256 + blk*16) = pack8(a, c);
    }
  } else if (b == 297){
    // fw1, fsw -> bf16 plain [128][32]
    const int k = tid >> 1, v0 = (tid & 1) * 16;
    #pragma unroll
    for (int i = 0; i < 2; ++i){
      f32x4 a  = *(const f32x4*)(fw1 + k*32 + v0 + i*8);
      f32x4 c  = *(const f32x4*)(fw1 + k*32 + v0 + i*8 + 4);
      *(uint4*)(ws + WS_A_FW1 + (size_t)k*64 + (size_t)v0*2 + i*16) = pack8(a, c);
      f32x4 a2 = *(const f32x4*)(fsw + k*32 + v0 + i*8);
      f32x4 c2 = *(const f32x4*)(fsw + k*32 + v0 + i*8 + 4);
      *(uint4*)(ws + WS_A_FSW + (size_t)k*64 + (size_t)v0*2 + i*16) = pack8(a2, c2);
    }
  }
}

// ---------------------------------------------------------------------------
// K1 (R2-verbatim): flattened GRN -> softmax weights (d_out[W_OFF..]).
// ---------------------------------------------------------------------------
__global__ __launch_bounds__(256) void k1_flat(
  const float* __restrict__ x,   const float* __restrict__ fb1,
  const float* __restrict__ fb2, const float* __restrict__ fsb,
  const float* __restrict__ flnw,const float* __restrict__ flnb,
  const unsigned char* __restrict__ ws, float* __restrict__ out)
{
  __shared__ __align__(16) unsigned char ldsW[65536];
  __shared__ __align__(16) unsigned char ldsH[4][4096];
  const int tid = threadIdx.x;
  const int wid = tid >> 6, lane = tid & 63;
  const int tl = lane & 15, q = lane >> 4;
  const int t0 = blockIdx.x * 64;
  const int tw = t0 + wid * 16 + tl;

  { // stage fw2' and wg1' into LDS
    const uint4* s1 = (const uint4*)(ws + WS_A_FW2);
    const uint4* s2 = (const uint4*)(ws + WS_A_WG1);
    uint4* d1 = (uint4*)ldsW;
    uint4* d2 = (uint4*)(ldsW + 32768);
    #pragma unroll
    for (int i = 0; i < 8; ++i){ d1[tid + i*256] = s1[tid + i*256]; d2[tid + i*256] = s2[tid + i*256]; }
  }
  bf16x8 xf;
  {
    f32x4 a = *(const f32x4*)(x + (size_t)tw*32 + q*8);
    f32x4 c = *(const f32x4*)(x + (size_t)tw*32 + q*8 + 4);
    #pragma unroll
    for (int e = 0; e < 4; ++e){ xf[e] = (bf16_t)a[e]; xf[e+4] = (bf16_t)c[e]; }
  }
  __syncthreads();

  const unsigned swzt = (unsigned)(tl & 7) << 4;
  #pragma unroll
  for (int mt = 0; mt < 8; ++mt){
    const int row = mt*16 + tl;
    uint4 araw = *(const uint4*)(ws + WS_A_FW1 + (size_t)row*64 + q*16);
    f32x4 acc = *(const f32x4*)(fb1 + mt*16 + q*4);
    acc = mfma16(asbf(araw), xf, acc);
    ushort4 hb;
    hb.x = f2bfu(eluf(acc[0])); hb.y = f2bfu(eluf(acc[1]));
    hb.z = f2bfu(eluf(acc[2])); hb.w = f2bfu(eluf(acc[3]));
    *(ushort4*)(ldsH[wid] + (unsigned)tl*256 + (((unsigned)(mt*32 + q*8)) ^ swzt)) = hb;
  }
  bf16x8 h1f[4];
  #pragma unroll
  for (int kb = 0; kb < 4; ++kb)
    h1f[kb] = asbf(*(const uint4*)(ldsH[wid] + (unsigned)tl*256 + (((unsigned)(kb*64 + q*16)) ^ swzt)));

  f32x4 wo[8];
  const float* bg1p = (const float*)(ws + WS_BG1);
  #pragma unroll
  for (int mt = 0; mt < 8; ++mt){
    const int row = mt*16 + tl;
    const uint4* aw = (const uint4*)(ldsW + (size_t)row*256);
    const uint4* ag = (const uint4*)(ldsW + 32768 + (size_t)row*256);
    const unsigned rsw = (unsigned)(row & 7);
    f32x4 h2 = *(const f32x4*)(fb2 + mt*16 + q*4);
    f32x4 gp = *(const f32x4*)(bg1p + mt*16 + q*4);
    #pragma unroll
    for (int kb = 0; kb < 4; ++kb){
      unsigned blk = (unsigned)(kb*4 + q) ^ rsw;
      h2 = mfma16(asbf(aw[blk]), h1f[kb], h2);
      gp = mfma16(asbf(ag[blk]), h1f[kb], gp);
    }
    uint4 asr = *(const uint4*)(ws + WS_A_FSW + (size_t)row*64 + q*16);
    f32x4 sk = *(const f32x4*)(fsb + mt*16 + q*4);
    sk = mfma16(asbf(asr), xf, sk);
    #pragma unroll
    for (int r = 0; r < 4; ++r){
      float g = sigmf(gp[r]);
      wo[mt][r] = sk[r] + g * (h2[r] - sk[r]);
    }
  }
  float sm = 0.f, sq = 0.f;
  #pragma unroll
  for (int mt = 0; mt < 8; ++mt)
  #pragma unroll
  for (int r = 0; r < 4; ++r){ float p = wo[mt][r]; sm += p; sq = fmaf(p, p, sq); }
  sm += __shfl_xor(sm, 16); sm += __shfl_xor(sm, 32);
  sq += __shfl_xor(sq, 16); sq += __shfl_xor(sq, 32);
  const float mean = sm * (1.f/128.f);
  const float var  = sq * (1.f/128.f) - mean*mean;
  const float rs   = __builtin_amdgcn_rsqf(var + 1e-5f);
  float wv[8];
  #pragma unroll
  for (int mt = 0; mt < 2; ++mt){
    f32x4 lw = *(const f32x4*)(flnw + mt*16 + q*4);
    f32x4 lb = *(const f32x4*)(flnb + mt*16 + q*4);
    #pragma unroll
    for (int r = 0; r < 4; ++r) wv[mt*4+r] = (wo[mt][r] - mean) * rs * lw[r] + lb[r];
  }
  float mx = wv[0];
  #pragma unroll
  for (int j = 1; j < 8; ++j) mx = fmaxf(mx, wv[j]);
  mx = fmaxf(mx, __shfl_xor(mx, 16)); mx = fmaxf(mx, __shfl_xor(mx, 32));
  float se = 0.f;
  #pragma unroll
  for (int j = 0; j < 8; ++j){ wv[j] = __expf(wv[j] - mx); se += wv[j]; }
  se += __shfl_xor(se, 16); se += __shfl_xor(se, 32);
  const float inv = __builtin_amdgcn_rcpf(se);
  #pragma unroll
  for (int mt = 0; mt < 2; ++mt)
  #pragma unroll
  for (int r = 0; r < 4; ++r)
    out[(size_t)W_OFF + (size_t)tw*32 + mt*16 + q*4 + r] = wv[mt*4+r] * inv;
}

// ---------------------------------------------------------------------------
// K2 (R7): block = 16 tokens x ALL 32 vars; wave w owns var octet [8w, 8w+8)
// for the SAME 16 tokens. Live state halved vs R2/R6 (sel[8]+pre[8] = 64 f32)
// so everything fits the 128-VGPR allocation -> no scratch spills (R5/R6:
// 200-360MB WRITE_SIZE of spill traffic). A-fragments stream from ws
// (L2-resident via XCD-clustered remap). Per-element math identical to R2.
// Tail: cross-wave LDS reduce (32KB) + single coalesced store.
// ---------------------------------------------------------------------------
__global__ __launch_bounds__(256, 4) void k2_main(
  const float* __restrict__ x,   const float* __restrict__ vw1,
  const float* __restrict__ vb1, const float* __restrict__ vb2,
  const float* __restrict__ vsw, const float* __restrict__ vsb,
  const float* __restrict__ vlnw,const float* __restrict__ vlnb,
  const unsigned char* __restrict__ ws, float* out)
{
  __shared__ __align__(16) unsigned char ldsR[32768];   // [4 wid][16 tok][512B]
  const int tid = threadIdx.x;
  const int wid = tid >> 6, lane = tid & 63;
  const int tl = lane & 15, q = lane >> 4;
  const int bid = blockIdx.x;
  const int t0 = ((bid & 7) * 128 + (bid >> 3)) * 16;   // XCD-clustered remap (1024 blocks)
  const int v0 = wid * 8;
  const int ta = t0 + tl;
  const float* bg2p = (const float*)(ws + WS_BG2);
  const f32x4 zero4 = {0.f,0.f,0.f,0.f};

  f32x4 sel[8];
  #pragma unroll
  for (int mt = 0; mt < 8; ++mt) sel[mt] = zero4;

  for (int vi = 0; vi < 8; ++vi){
    const int v = v0 + vi;
    const float xv0 = x[(size_t)ta*32 + v];
    const float wt0 = out[(size_t)W_OFF + (size_t)ta*32 + v];

    // B-fragment: hv1 = elu(x*vw1 + vb1), elem e <-> h = kb*32 + 8q + e
    bf16x8 bf0[4];
    #pragma unroll
    for (int kb = 0; kb < 4; ++kb){
      const float* wp = vw1 + v*128 + kb*32 + q*8;
      const float* bp = vb1 + v*128 + kb*32 + q*8;
      f32x4 w0v = *(const f32x4*)wp, w1v = *(const f32x4*)(wp + 4);
      f32x4 b0v = *(const f32x4*)bp, b1v = *(const f32x4*)(bp + 4);
      bf16x8 f0;
      #pragma unroll
      for (int e = 0; e < 4; ++e){
        f0[e]   = (bf16_t)eluf(fmaf(xv0, w0v[e], b0v[e]));
        f0[e+4] = (bf16_t)eluf(fmaf(xv0, w1v[e], b1v[e]));
      }
      bf0[kb] = f0;
    }

    // fused GEMMs: hv2 and gate share bf0; A/G frags direct from L2
    const unsigned char* wsA = ws + WS_A_VW2 + (size_t)v*32768 + (size_t)tl*256 + (size_t)q*16;
    const unsigned char* wsG = ws + WS_A_WG2 + (size_t)v*32768 + (size_t)tl*256 + (size_t)q*16;
    f32x4 pre[8];
    #pragma unroll
    for (int mt = 0; mt < 8; ++mt){
      f32x4 h0 = *(const f32x4*)(vb2 + v*128 + mt*16 + q*4);
      f32x4 g0 = *(const f32x4*)(bg2p + v*128 + mt*16 + q*4);
      #pragma unroll
      for (int kb = 0; kb < 4; ++kb){
        bf16x8 a = asbf(*(const uint4*)(wsA + mt*4096 + kb*64));
        h0 = mfma16(a, bf0[kb], h0);
      }
      #pragma unroll
      for (int kb = 0; kb < 4; ++kb){
        bf16x8 g = asbf(*(const uint4*)(wsG + mt*4096 + kb*64));
        g0 = mfma16(g, bf0[kb], g0);
      }
      f32x4 sw_ = *(const f32x4*)(vsw + v*128 + mt*16 + q*4);
      f32x4 sb_ = *(const f32x4*)(vsb + v*128 + mt*16 + q*4);
      #pragma unroll
      for (int r = 0; r < 4; ++r){
        float sk0 = fmaf(xv0, sw_[r], sb_[r]);
        pre[mt][r] = sk0 + sigmf(g0[r]) * (h0[r] - sk0);
      }
    }

    // LayerNorm + weighted select accumulation
    {
      float sm = 0.f, sq = 0.f;
      #pragma unroll
      for (int mt = 0; mt < 8; ++mt)
      #pragma unroll
      for (int r = 0; r < 4; ++r){ float p = pre[mt][r]; sm += p; sq = fmaf(p, p, sq); }
      sm += __shfl_xor(sm, 16); sm += __shfl_xor(sm, 32);
      sq += __shfl_xor(sq, 16); sq += __shfl_xor(sq, 32);
      const float mean = sm * (1.f/128.f);
      const float var  = sq * (1.f/128.f) - mean*mean;
      const float rsq  = __builtin_amdgcn_rsqf(var + 1e-5f);
      const float c1   = wt0 * rsq;
      #pragma unroll
      for (int mt = 0; mt < 8; ++mt){
        f32x4 lw = *(const f32x4*)(vlnw + v*128 + mt*16 + q*4);
        f32x4 lb = *(const f32x4*)(vlnb + v*128 + mt*16 + q*4);
        #pragma unroll
        for (int r = 0; r < 4; ++r)
          sel[mt][r] = fmaf((pre[mt][r] - mean) * lw[r], c1,
                            fmaf(wt0, lb[r], sel[mt][r]));
      }
    }
  }

  // tail: cross-wave reduce in LDS (XOR-swizzled 16B blocks), single store
  #pragma unroll
  for (int mt = 0; mt < 8; ++mt){
    const unsigned blk = (unsigned)(mt*4 + q) ^ (unsigned)(tl & 7);
    *(f32x4*)(ldsR + (size_t)wid*8192 + (size_t)tl*512 + blk*16) = sel[mt];
  }
  __syncthreads();
  {
    const int tok = tid >> 4;        // 16 tokens x 16 threads
    const int bl  = tid & 15;
    #pragma unroll
    for (int j = 0; j < 2; ++j){
      const int blk_lin = bl + 16*j;
      const unsigned phys = (unsigned)blk_lin ^ (unsigned)(tok & 7);
      f32x4 s = {0.f,0.f,0.f,0.f};
      #pragma unroll
      for (int w = 0; w < 4; ++w){
        f32x4 p = *(const f32x4*)(ldsR + (size_t)w*8192 + (size_t)tok*512 + phys*16);
        #pragma unroll
        for (int r = 0; r < 4; ++r) s[r] += p[r];
      }
      *(f32x4*)(out + (size_t)(t0 + tok)*128 + blk_lin*4) = s;
    }
  }
}

// ---------------------------------------------------------------------------
extern "C" void kernel_launch(void* const* d_in, const int* in_sizes, int n_in,
                              void* d_out, int out_size, void* d_ws, size_t ws_size,
                              hipStream_t stream)
{
  (void)in_sizes; (void)n_in; (void)out_size; (void)ws_size;
  const float* x    = (const float*)d_in[0];
  const float* fw1  = (const float*)d_in[1];
  const float* fb1  = (const float*)d_in[2];
  const float* fw2  = (const float*)d_in[3];
  const float* fb2  = (const float*)d_in[4];
  const float* fgw  = (const float*)d_in[5];
  const float* fgb  = (const float*)d_in[6];
  const float* fsw  = (const float*)d_in[7];
  const float* fsb  = (const float*)d_in[8];
  const float* flnw = (const float*)d_in[9];
  const float* flnb = (const float*)d_in[10];
  const float* vw1  = (const float*)d_in[11];
  const float* vb1  = (const float*)d_in[12];
  const float* vw2  = (const float*)d_in[13];
  const float* vb2  = (const float*)d_in[14];
  const float* vgw  = (const float*)d_in[15];
  const float* vgb  = (const float*)d_in[16];
  const float* vsw  = (const float*)d_in[17];
  const float* vsb  = (const float*)d_in[18];
  const float* vlnw = (const float*)d_in[19];
  const float* vlnb = (const float*)d_in[20];
  float* out = (float*)d_out;
  unsigned char* ws = (unsigned char*)d_ws;

  k0_prep<<<298, 256, 0, stream>>>(fw1, fw2, fgw, fgb, fb2, fsw, vw2, vgw, vgb, vb2, ws);
  k1_flat<<<256, 256, 0, stream>>>(x, fb1, fb2, fsb, flnw, flnb, ws, out);
  k2_main<<<1024, 256, 0, stream>>>(x, vw1, vb1, vb2, vsw, vsb, vlnw, vlnb, ws, out);
}

// Round 8
// 192.591 us; speedup vs baseline: 2.4002x; 2.4002x over previous
//
#include <hip/hip_runtime.h>
#include <hip/hip_bf16.h>

typedef __bf16 bf16_t;
typedef __bf16 bf16x8 __attribute__((ext_vector_type(8)));
typedef float  f32x4  __attribute__((ext_vector_type(4)));

#define DEVFN static __device__ __forceinline__

constexpr int TOK   = 32 * 512;        // 16384 tokens
constexpr int W_OFF = TOK * 128;       // weights offset (floats) in d_out

// d_ws byte offsets
constexpr size_t WS_A_VW2 = 0;                                  // 1MB (bf16, plain rows)
constexpr size_t WS_A_WG2 = (size_t)1 << 20;                    // 1MB (bf16, plain rows)
constexpr size_t WS_BG2   = (size_t)2 << 20;                    // 16KB f32 [32][128]
constexpr size_t WS_A_FW2 = ((size_t)2 << 20) + (64u  << 10);   // 32KB (bf16, XOR-swizzled for k1 LDS)
constexpr size_t WS_A_WG1 = ((size_t)2 << 20) + (128u << 10);   // 32KB (bf16, XOR-swizzled for k1 LDS)
constexpr size_t WS_BG1   = ((size_t)2 << 20) + (192u << 10);   // 512B f32 [128]
constexpr size_t WS_A_FW1 = ((size_t)2 << 20) + (224u << 10);   // 8KB  (bf16, plain)
constexpr size_t WS_A_FSW = ((size_t)2 << 20) + (256u << 10);   // 8KB  (bf16, plain)

DEVFN float eluf(float z)  { return z > 0.0f ? z : (__expf(z) - 1.0f); }
DEVFN float sigmf(float z) { return __builtin_amdgcn_rcpf(1.0f + __expf(-z)); }
DEVFN unsigned short f2bfu(float f){ bf16_t h = (bf16_t)f; return __builtin_bit_cast(unsigned short, h); }

DEVFN uint4 pack8(f32x4 a, f32x4 b){
  uint4 r;
  r.x = (unsigned)f2bfu(a[0]) | ((unsigned)f2bfu(a[1]) << 16);
  r.y = (unsigned)f2bfu(a[2]) | ((unsigned)f2bfu(a[3]) << 16);
  r.z = (unsigned)f2bfu(b[0]) | ((unsigned)f2bfu(b[1]) << 16);
  r.w = (unsigned)f2bfu(b[2]) | ((unsigned)f2bfu(b[3]) << 16);
  return r;
}
DEVFN f32x4 mfma16(bf16x8 a, bf16x8 b, f32x4 c){
  return __builtin_amdgcn_mfma_f32_16x16x32_bf16(a, b, c, 0, 0, 0);
}
DEVFN bf16x8 asbf(uint4 u){ return __builtin_bit_cast(bf16x8, u); }

// ---------------------------------------------------------------------------
// K0 (R2-verbatim): fused gate matrices (Wg2 = vgw·vw2, Wg1 = fgw·fw2, fused
// biases), bf16 packing. VW2/WG2 slabs: PLAIN row-major [128][128] bf16.
// FW2/WG1 slabs: XOR-swizzled (k1 stages them in LDS).
// ---------------------------------------------------------------------------
__global__ void k0_prep(const float* __restrict__ fw1, const float* __restrict__ fw2,
                        const float* __restrict__ fgw, const float* __restrict__ fgb,
                        const float* __restrict__ fb2, const float* __restrict__ fsw,
                        const float* __restrict__ vw2, const float* __restrict__ vgw,
                        const float* __restrict__ vgb, const float* __restrict__ vb2,
                        unsigned char* __restrict__ ws)
{
  const int b = blockIdx.x, tid = threadIdx.x;
  if (b < 256){
    // Wg2 = vgw[v] @ vw2[v]: v = b>>3, 16 rows/block, thread: 1 row x 8 cols
    const int v  = b >> 3;
    const int k2 = (b & 7) * 16 + (tid >> 4);
    const int h0 = (tid & 15) * 8;
    const float* gw = vgw + ((size_t)v * 128 + k2) * 128;
    const float* w2 = vw2 + (size_t)v * 128 * 128;
    f32x4 a0 = {0,0,0,0}, a1 = {0,0,0,0};
    for (int k = 0; k < 128; ++k){
      float a = gw[k];
      f32x4 u = *(const f32x4*)(w2 + k*128 + h0);
      f32x4 w = *(const f32x4*)(w2 + k*128 + h0 + 4);
      #pragma unroll
      for (int e = 0; e < 4; ++e){ a0[e] = fmaf(a, u[e], a0[e]); a1[e] = fmaf(a, w[e], a1[e]); }
    }
    *(uint4*)(ws + WS_A_WG2 + (size_t)v*32768 + (size_t)k2*256 + (size_t)h0*2) = pack8(a0, a1);
    if ((b & 7) == 0 && tid < 128){
      const float* gr = vgw + ((size_t)v*128 + tid) * 128;
      const float* vb = vb2 + v*128;
      float s = vgb[v*128 + tid];
      for (int k = 0; k < 128; ++k) s = fmaf(gr[k], vb[k], s);
      ((float*)(ws + WS_BG2))[v*128 + tid] = s;
    }
  } else if (b < 288){
    // vw2 -> bf16 plain rows
    const int v = b - 256;
    const int k = tid >> 1, hh = (tid & 1) * 64;
    const float* src = vw2 + ((size_t)v*128 + k) * 128;
    #pragma unroll
    for (int i = 0; i < 8; ++i){
      int h0 = hh + i*8;
      f32x4 a = *(const f32x4*)(src + h0);
      f32x4 c = *(const f32x4*)(src + h0 + 4);
      *(uint4*)(ws + WS_A_VW2 + (size_t)v*32768 + (size_t)k*256 + (size_t)h0*2) = pack8(a, c);
    }
  } else if (b < 296){
    // Wg1 = fgw @ fw2 (+ bg1), XOR-swizzled for k1's LDS use
    const int k2 = (b - 288) * 16 + (tid >> 4);
    const int h0 = (tid & 15) * 8;
    const float* gw = fgw + (size_t)k2 * 128;
    f32x4 a0 = {0,0,0,0}, a1 = {0,0,0,0};
    for (int k = 0; k < 128; ++k){
      float a = gw[k];
      f32x4 u = *(const f32x4*)(fw2 + k*128 + h0);
      f32x4 w = *(const f32x4*)(fw2 + k*128 + h0 + 4);
      #pragma unroll
      for (int e = 0; e < 4; ++e){ a0[e] = fmaf(a, u[e], a0[e]); a1[e] = fmaf(a, w[e], a1[e]); }
    }
    unsigned blk = (unsigned)(h0 >> 3) ^ (unsigned)(k2 & 7);
    *(uint4*)(ws + WS_A_WG1 + (size_t)k2*256 + blk*16) = pack8(a0, a1);
    if (b == 288 && tid < 128){
      const float* gr = fgw + (size_t)tid * 128;
      float s = fgb[tid];
      for (int k = 0; k < 128; ++k) s = fmaf(gr[k], fb2[k], s);
      ((float*)(ws + WS_BG1))[tid] = s;
    }
  } else if (b == 296){
    // fw2 -> bf16 XOR-swizzled
    const int k = tid >> 1, hh = (tid & 1) * 64;
    const float* src = fw2 + (size_t)k * 128;
    #pragma unroll
    for (int i = 0; i < 8; ++i){
      int h0 = hh + i*8;
      f32x4 a = *(const f32x4*)(src + h0);
      f32x4 c = *(const f32x4*)(src + h0 + 4);
      unsigned blk = (unsigned)(h0 >> 3) ^ (unsigned)(k & 7);
      *(uint4*)(ws + WS_A_FW2 + (size_t)k*256 + blk*16) = pack8(a, c);
    }
  } else if (b == 297){
    // fw1, fsw -> bf16 plain [128][32]
    const int k = tid >> 1, v0 = (tid & 1) * 16;
    #pragma unroll
    for (int i = 0; i < 2; ++i){
      f32x4 a  = *(const f32x4*)(fw1 + k*32 + v0 + i*8);
      f32x4 c  = *(const f32x4*)(fw1 + k*32 + v0 + i*8 + 4);
      *(uint4*)(ws + WS_A_FW1 + (size_t)k*64 + (size_t)v0*2 + i*16) = pack8(a, c);
      f32x4 a2 = *(const f32x4*)(fsw + k*32 + v0 + i*8);
      f32x4 c2 = *(const f32x4*)(fsw + k*32 + v0 + i*8 + 4);
      *(uint4*)(ws + WS_A_FSW + (size_t)k*64 + (size_t)v0*2 + i*16) = pack8(a2, c2);
    }
  }
}

// ---------------------------------------------------------------------------
// K1 (R2-verbatim): flattened GRN -> softmax weights (d_out[W_OFF..]).
// ---------------------------------------------------------------------------
__global__ __launch_bounds__(256) void k1_flat(
  const float* __restrict__ x,   const float* __restrict__ fb1,
  const float* __restrict__ fb2, const float* __restrict__ fsb,
  const float* __restrict__ flnw,const float* __restrict__ flnb,
  const unsigned char* __restrict__ ws, float* __restrict__ out)
{
  __shared__ __align__(16) unsigned char ldsW[65536];
  __shared__ __align__(16) unsigned char ldsH[4][4096];
  const int tid = threadIdx.x;
  const int wid = tid >> 6, lane = tid & 63;
  const int tl = lane & 15, q = lane >> 4;
  const int t0 = blockIdx.x * 64;
  const int tw = t0 + wid * 16 + tl;

  { // stage fw2' and wg1' into LDS
    const uint4* s1 = (const uint4*)(ws + WS_A_FW2);
    const uint4* s2 = (const uint4*)(ws + WS_A_WG1);
    uint4* d1 = (uint4*)ldsW;
    uint4* d2 = (uint4*)(ldsW + 32768);
    #pragma unroll
    for (int i = 0; i < 8; ++i){ d1[tid + i*256] = s1[tid + i*256]; d2[tid + i*256] = s2[tid + i*256]; }
  }
  bf16x8 xf;
  {
    f32x4 a = *(const f32x4*)(x + (size_t)tw*32 + q*8);
    f32x4 c = *(const f32x4*)(x + (size_t)tw*32 + q*8 + 4);
    #pragma unroll
    for (int e = 0; e < 4; ++e){ xf[e] = (bf16_t)a[e]; xf[e+4] = (bf16_t)c[e]; }
  }
  __syncthreads();

  const unsigned swzt = (unsigned)(tl & 7) << 4;
  #pragma unroll
  for (int mt = 0; mt < 8; ++mt){
    const int row = mt*16 + tl;
    uint4 araw = *(const uint4*)(ws + WS_A_FW1 + (size_t)row*64 + q*16);
    f32x4 acc = *(const f32x4*)(fb1 + mt*16 + q*4);
    acc = mfma16(asbf(araw), xf, acc);
    ushort4 hb;
    hb.x = f2bfu(eluf(acc[0])); hb.y = f2bfu(eluf(acc[1]));
    hb.z = f2bfu(eluf(acc[2])); hb.w = f2bfu(eluf(acc[3]));
    *(ushort4*)(ldsH[wid] + (unsigned)tl*256 + (((unsigned)(mt*32 + q*8)) ^ swzt)) = hb;
  }
  bf16x8 h1f[4];
  #pragma unroll
  for (int kb = 0; kb < 4; ++kb)
    h1f[kb] = asbf(*(const uint4*)(ldsH[wid] + (unsigned)tl*256 + (((unsigned)(kb*64 + q*16)) ^ swzt)));

  f32x4 wo[8];
  const float* bg1p = (const float*)(ws + WS_BG1);
  #pragma unroll
  for (int mt = 0; mt < 8; ++mt){
    const int row = mt*16 + tl;
    const uint4* aw = (const uint4*)(ldsW + (size_t)row*256);
    const uint4* ag = (const uint4*)(ldsW + 32768 + (size_t)row*256);
    const unsigned rsw = (unsigned)(row & 7);
    f32x4 h2 = *(const f32x4*)(fb2 + mt*16 + q*4);
    f32x4 gp = *(const f32x4*)(bg1p + mt*16 + q*4);
    #pragma unroll
    for (int kb = 0; kb < 4; ++kb){
      unsigned blk = (unsigned)(kb*4 + q) ^ rsw;
      h2 = mfma16(asbf(aw[blk]), h1f[kb], h2);
      gp = mfma16(asbf(ag[blk]), h1f[kb], gp);
    }
    uint4 asr = *(const uint4*)(ws + WS_A_FSW + (size_t)row*64 + q*16);
    f32x4 sk = *(const f32x4*)(fsb + mt*16 + q*4);
    sk = mfma16(asbf(asr), xf, sk);
    #pragma unroll
    for (int r = 0; r < 4; ++r){
      float g = sigmf(gp[r]);
      wo[mt][r] = sk[r] + g * (h2[r] - sk[r]);
    }
  }
  float sm = 0.f, sq = 0.f;
  #pragma unroll
  for (int mt = 0; mt < 8; ++mt)
  #pragma unroll
  for (int r = 0; r < 4; ++r){ float p = wo[mt][r]; sm += p; sq = fmaf(p, p, sq); }
  sm += __shfl_xor(sm, 16); sm += __shfl_xor(sm, 32);
  sq += __shfl_xor(sq, 16); sq += __shfl_xor(sq, 32);
  const float mean = sm * (1.f/128.f);
  const float var  = sq * (1.f/128.f) - mean*mean;
  const float rs   = __builtin_amdgcn_rsqf(var + 1e-5f);
  float wv[8];
  #pragma unroll
  for (int mt = 0; mt < 2; ++mt){
    f32x4 lw = *(const f32x4*)(flnw + mt*16 + q*4);
    f32x4 lb = *(const f32x4*)(flnb + mt*16 + q*4);
    #pragma unroll
    for (int r = 0; r < 4; ++r) wv[mt*4+r] = (wo[mt][r] - mean) * rs * lw[r] + lb[r];
  }
  float mx = wv[0];
  #pragma unroll
  for (int j = 1; j < 8; ++j) mx = fmaxf(mx, wv[j]);
  mx = fmaxf(mx, __shfl_xor(mx, 16)); mx = fmaxf(mx, __shfl_xor(mx, 32));
  float se = 0.f;
  #pragma unroll
  for (int j = 0; j < 8; ++j){ wv[j] = __expf(wv[j] - mx); se += wv[j]; }
  se += __shfl_xor(se, 16); se += __shfl_xor(se, 32);
  const float inv = __builtin_amdgcn_rcpf(se);
  #pragma unroll
  for (int mt = 0; mt < 2; ++mt)
  #pragma unroll
  for (int r = 0; r < 4; ++r)
    out[(size_t)W_OFF + (size_t)tw*32 + mt*16 + q*4 + r] = wv[mt*4+r] * inv;
}

// ---------------------------------------------------------------------------
// K2 (R8): R2 geometry — block = 32 tokens x ALL 32 vars, wave owns v-octet,
// XCD-clustered remap, slabs streamed from L2. Anti-spill restructure:
// `pre` lives in LDS (lane-major contiguous planes -> conflict-free b128),
// sm/sq accumulated on the fly; sel stays in registers. launch_bounds(256,1)
// lets the allocator use up to 512 VGPRs (observed heuristic picks ~2x min
// occupancy => ~256). LDS (64KB) caps occupancy at 2 blocks/CU anyway.
// Per-element math identical to R2 (absmax 0.0078).
// ---------------------------------------------------------------------------
__global__ __launch_bounds__(256, 1) void k2_main(
  const float* __restrict__ x,   const float* __restrict__ vw1,
  const float* __restrict__ vb1, const float* __restrict__ vb2,
  const float* __restrict__ vsw, const float* __restrict__ vsb,
  const float* __restrict__ vlnw,const float* __restrict__ vlnb,
  const unsigned char* __restrict__ ws, float* out)
{
  // union: [vi loop] pre planes (wave-private, lane-major):
  //          addr = wid*16K + (nt*8+mt)*1K + lane*16
  //        [tail]   cross-wave reduce [wid][tok 32][512B]  (after barrier)
  __shared__ __align__(16) unsigned char ldsP[65536];
  const int tid = threadIdx.x;
  const int wid = tid >> 6, lane = tid & 63;
  const int tl = lane & 15, q = lane >> 4;
  const int bid = blockIdx.x;
  const int t0 = ((bid & 7) * 64 + (bid >> 3)) * 32;    // XCD-clustered remap
  const int v0 = wid * 8;
  const int ta = t0 + tl, tb = t0 + 16 + tl;
  const float* bg2p = (const float*)(ws + WS_BG2);
  const f32x4 zero4 = {0.f,0.f,0.f,0.f};

  unsigned char* preW = ldsP + (size_t)wid*16384 + (size_t)lane*16;

  f32x4 sel[2][8];   // [nt][mt]
  #pragma unroll
  for (int mt = 0; mt < 8; ++mt){ sel[0][mt] = zero4; sel[1][mt] = zero4; }

  for (int vi = 0; vi < 8; ++vi){
    const int v = v0 + vi;
    const float xv0 = x[(size_t)ta*32 + v];
    const float xv1 = x[(size_t)tb*32 + v];
    const float wt0 = out[(size_t)W_OFF + (size_t)ta*32 + v];
    const float wt1 = out[(size_t)W_OFF + (size_t)tb*32 + v];

    // B-fragments: hv1 = elu(x*vw1 + vb1), elem e <-> h = kb*32 + 8q + e
    bf16x8 bf0[4], bf1[4];
    #pragma unroll
    for (int kb = 0; kb < 4; ++kb){
      const float* wp = vw1 + v*128 + kb*32 + q*8;
      const float* bp = vb1 + v*128 + kb*32 + q*8;
      f32x4 w0v = *(const f32x4*)wp, w1v = *(const f32x4*)(wp + 4);
      f32x4 b0v = *(const f32x4*)bp, b1v = *(const f32x4*)(bp + 4);
      bf16x8 f0, f1;
      #pragma unroll
      for (int e = 0; e < 4; ++e){
        f0[e]   = (bf16_t)eluf(fmaf(xv0, w0v[e], b0v[e]));
        f0[e+4] = (bf16_t)eluf(fmaf(xv0, w1v[e], b1v[e]));
        f1[e]   = (bf16_t)eluf(fmaf(xv1, w0v[e], b0v[e]));
        f1[e+4] = (bf16_t)eluf(fmaf(xv1, w1v[e], b1v[e]));
      }
      bf0[kb] = f0; bf1[kb] = f1;
    }

    // phase 1: fused GEMMs (hv2 + gate share bfrag), combine with skip,
    // write pre to LDS planes, accumulate sm/sq on the fly.
    const unsigned char* wsA = ws + WS_A_VW2 + (size_t)v*32768 + (size_t)tl*256 + (size_t)q*16;
    const unsigned char* wsG = ws + WS_A_WG2 + (size_t)v*32768 + (size_t)tl*256 + (size_t)q*16;
    float sm0 = 0.f, sq0 = 0.f, sm1 = 0.f, sq1 = 0.f;
    #pragma unroll
    for (int mt = 0; mt < 8; ++mt){
      f32x4 bini = *(const f32x4*)(vb2 + v*128 + mt*16 + q*4);
      f32x4 gini = *(const f32x4*)(bg2p + v*128 + mt*16 + q*4);
      f32x4 h0 = bini, h1 = bini, g0 = gini, g1 = gini;
      #pragma unroll
      for (int kb = 0; kb < 4; ++kb){
        bf16x8 a = asbf(*(const uint4*)(wsA + mt*4096 + kb*64));
        h0 = mfma16(a, bf0[kb], h0);
        h1 = mfma16(a, bf1[kb], h1);
      }
      #pragma unroll
      for (int kb = 0; kb < 4; ++kb){
        bf16x8 g = asbf(*(const uint4*)(wsG + mt*4096 + kb*64));
        g0 = mfma16(g, bf0[kb], g0);
        g1 = mfma16(g, bf1[kb], g1);
      }
      f32x4 sw_ = *(const f32x4*)(vsw + v*128 + mt*16 + q*4);
      f32x4 sb_ = *(const f32x4*)(vsb + v*128 + mt*16 + q*4);
      f32x4 p0, p1;
      #pragma unroll
      for (int r = 0; r < 4; ++r){
        float sk0 = fmaf(xv0, sw_[r], sb_[r]);
        float sk1 = fmaf(xv1, sw_[r], sb_[r]);
        p0[r] = sk0 + sigmf(g0[r]) * (h0[r] - sk0);
        p1[r] = sk1 + sigmf(g1[r]) * (h1[r] - sk1);
        sm0 += p0[r]; sq0 = fmaf(p0[r], p0[r], sq0);
        sm1 += p1[r]; sq1 = fmaf(p1[r], p1[r], sq1);
      }
      *(f32x4*)(preW + (unsigned)(mt      )*1024) = p0;   // nt=0 plane
      *(f32x4*)(preW + (unsigned)(8 + mt  )*1024) = p1;   // nt=1 plane
    }

    // phase 2: LayerNorm + weighted select accumulation (pre read from LDS)
    sm0 += __shfl_xor(sm0, 16); sm0 += __shfl_xor(sm0, 32);
    sq0 += __shfl_xor(sq0, 16); sq0 += __shfl_xor(sq0, 32);
    sm1 += __shfl_xor(sm1, 16); sm1 += __shfl_xor(sm1, 32);
    sq1 += __shfl_xor(sq1, 16); sq1 += __shfl_xor(sq1, 32);
    const float mean0 = sm0 * (1.f/128.f);
    const float mean1 = sm1 * (1.f/128.f);
    const float rsq0  = __builtin_amdgcn_rsqf(sq0 * (1.f/128.f) - mean0*mean0 + 1e-5f);
    const float rsq1  = __builtin_amdgcn_rsqf(sq1 * (1.f/128.f) - mean1*mean1 + 1e-5f);
    const float c10 = wt0 * rsq0, c11 = wt1 * rsq1;
    #pragma unroll
    for (int mt = 0; mt < 8; ++mt){
      f32x4 lw = *(const f32x4*)(vlnw + v*128 + mt*16 + q*4);
      f32x4 lb = *(const f32x4*)(vlnb + v*128 + mt*16 + q*4);
      f32x4 p0 = *(const f32x4*)(preW + (unsigned)(mt     )*1024);
      f32x4 p1 = *(const f32x4*)(preW + (unsigned)(8 + mt )*1024);
      #pragma unroll
      for (int r = 0; r < 4; ++r){
        sel[0][mt][r] = fmaf((p0[r] - mean0) * lw[r], c10, fmaf(wt0, lb[r], sel[0][mt][r]));
        sel[1][mt][r] = fmaf((p1[r] - mean1) * lw[r], c11, fmaf(wt1, lb[r], sel[1][mt][r]));
      }
    }
  }

  // tail: cross-wave reduce (reuses ldsP; regions wave-private until barrier)
  #pragma unroll
  for (int mt = 0; mt < 8; ++mt)
  #pragma unroll
  for (int nt = 0; nt < 2; ++nt){
    const int tok = nt*16 + tl;
    const unsigned blk = (unsigned)(mt*4 + q) ^ (unsigned)(tok & 7);
    *(f32x4*)(ldsP + (size_t)wid*16384 + (size_t)tok*512 + blk*16) = sel[nt][mt];
  }
  __syncthreads();
  {
    const int tok = tid >> 3;
    const int bl  = tid & 7;
    #pragma unroll
    for (int j = 0; j < 4; ++j){
      const int blk_lin = bl + 8*j;
      const unsigned phys = (unsigned)blk_lin ^ (unsigned)(tok & 7);
      f32x4 s = {0.f,0.f,0.f,0.f};
      #pragma unroll
      for (int w = 0; w < 4; ++w){
        f32x4 p = *(const f32x4*)(ldsP + (size_t)w*16384 + (size_t)tok*512 + phys*16);
        #pragma unroll
        for (int r = 0; r < 4; ++r) s[r] += p[r];
      }
      *(f32x4*)(out + (size_t)(t0 + tok)*128 + blk_lin*4) = s;
    }
  }
}

// ---------------------------------------------------------------------------
extern "C" void kernel_launch(void* const* d_in, const int* in_sizes, int n_in,
                              void* d_out, int out_size, void* d_ws, size_t ws_size,
                              hipStream_t stream)
{
  (void)in_sizes; (void)n_in; (void)out_size; (void)ws_size;
  const float* x    = (const float*)d_in[0];
  const float* fw1  = (const float*)d_in[1];
  const float* fb1  = (const float*)d_in[2];
  const float* fw2  = (const float*)d_in[3];
  const float* fb2  = (const float*)d_in[4];
  const float* fgw  = (const float*)d_in[5];
  const float* fgb  = (const float*)d_in[6];
  const float* fsw  = (const float*)d_in[7];
  const float* fsb  = (const float*)d_in[8];
  const float* flnw = (const float*)d_in[9];
  const float* flnb = (const float*)d_in[10];
  const float* vw1  = (const float*)d_in[11];
  const float* vb1  = (const float*)d_in[12];
  const float* vw2  = (const float*)d_in[13];
  const float* vb2  = (const float*)d_in[14];
  const float* vgw  = (const float*)d_in[15];
  const float* vgb  = (const float*)d_in[16];
  const float* vsw  = (const float*)d_in[17];
  const float* vsb  = (const float*)d_in[18];
  const float* vlnw = (const float*)d_in[19];
  const float* vlnb = (const float*)d_in[20];
  float* out = (float*)d_out;
  unsigned char* ws = (unsigned char*)d_ws;

  k0_prep<<<298, 256, 0, stream>>>(fw1, fw2, fgw, fgb, fb2, fsw, vw2, vgw, vgb, vb2, ws);
  k1_flat<<<256, 256, 0, stream>>>(x, fb1, fb2, fsb, flnw, flnb, ws, out);
  k2_main<<<512, 256, 0, stream>>>(x, vw1, vb1, vb2, vsw, vsb, vlnw, vlnb, ws, out);
}